// Round 3
// baseline (1368.228 us; speedup 1.0000x reference)
//
#include <hip/hip_runtime.h>
#include <hip/hip_bf16.h>

typedef __bf16 bf16_t;
typedef __bf16 bf16x8 __attribute__((ext_vector_type(8)));
typedef float f32x4 __attribute__((ext_vector_type(4)));

#define MODEL_DIM 1024
#define INNER 2048
#define STATE 16
#define BATCH 2
#define SEQ 1024
#define BS (BATCH * SEQ)            // 2048 rows
#define PROJ_N (2 * INNER)          // 4096
#define BCN (INNER * STATE)         // 32768
#define NCHUNK 64
#define CLEN (SEQ / NCHUNK)         // 16

// ---------------------------------------------------------------------------
// async global->LDS, 16B per lane (wave-uniform LDS base, HW adds lane*16)
// ---------------------------------------------------------------------------
__device__ __forceinline__ void load_lds_16B(const void* g, void* l) {
  __builtin_amdgcn_global_load_lds(
      (const __attribute__((address_space(1))) unsigned int*)g,
      (__attribute__((address_space(3))) unsigned int*)l,
      16, 0, 0);
}

// ---------------------------------------------------------------------------
// f32 -> bf16 cast (vectorized, grid-stride). n must be divisible by 4.
// ---------------------------------------------------------------------------
__global__ void cast_f32_bf16(const float* __restrict__ in,
                              bf16_t* __restrict__ out, long n4) {
  long idx = (long)blockIdx.x * blockDim.x + threadIdx.x;
  long stride = (long)gridDim.x * blockDim.x;
  for (long i = idx; i < n4; i += stride) {
    float4 v = ((const float4*)in)[i];
    union { bf16_t b[4]; ushort4 u; } cv;
    cv.b[0] = (bf16_t)v.x; cv.b[1] = (bf16_t)v.y;
    cv.b[2] = (bf16_t)v.z; cv.b[3] = (bf16_t)v.w;
    ((ushort4*)out)[i] = cv.u;
  }
}

// ---------------------------------------------------------------------------
// BIG GEMM: C[M,N] = A[M,K] * Bt[N,K]^T, bf16 out.  M=2048 fixed, N=32768.
// Tile 256x128, BK=64, 8 waves (wave grid 2Mx4N), per-wave C = 128x32.
// 3 LDS buffers (144KB), prefetch distance 2, counted vmcnt(6), never 0.
// LDS swizzle: 16B slot s_phys = s_log ^ (row&7)  (involution, both sides).
// Grid: 1D 2048 blocks; XCD-grouped mapping for L2/L3 locality.
// ---------------------------------------------------------------------------
__global__ __launch_bounds__(512, 2)
void gemm_big(const bf16_t* __restrict__ A, const bf16_t* __restrict__ Bt,
              bf16_t* __restrict__ C, int N, int K) {
  __shared__ bf16_t As[3 * 256 * 64];   // 96KB
  __shared__ bf16_t Bs[3 * 128 * 64];   // 48KB
  const int tid = threadIdx.x;
  const int wid = tid >> 6, lane = tid & 63;
  const int wm = wid >> 2, wn = wid & 3;

  // XCD-grouped block mapping: each XCD owns 32 bcols x 8 brows
  const int bid = blockIdx.x;
  const int xcd = bid & 7, local = bid >> 3;          // local 0..255
  const int bcol = (xcd * 32 + (local & 31)) * 128;
  const int brow = (local >> 5) * 256;

  // staging: per-thread source column (pre-swizzled so linear LDS dest is OK)
  const int srow8 = lane >> 3;                        // row&7 within 8-row strip
  const int scol = ((lane & 7) ^ srow8) * 8;          // bf16 elems

  const int NT = K >> 6;                              // K-tiles of 64

  // ds_read lane decomposition
  const int r15 = lane & 15, g = lane >> 4, l7 = lane & 7;

  f32x4 acc[8][2] = {};

#define STAGE(t)                                                              \
  {                                                                           \
    const int _b = (t) % 3;                                                   \
    const int _k0 = (t) * 64;                                                 \
    _Pragma("unroll")                                                         \
    for (int j = 0; j < 4; ++j) {                                             \
      int row = j * 64 + wid * 8 + srow8;                                     \
      load_lds_16B(A + (size_t)(brow + row) * K + _k0 + scol,                 \
                   (void*)(As + _b * 16384 + j * 4096 + wid * 512));          \
    }                                                                         \
    _Pragma("unroll")                                                         \
    for (int j = 0; j < 2; ++j) {                                             \
      int row = j * 64 + wid * 8 + srow8;                                     \
      load_lds_16B(Bt + (size_t)(bcol + row) * K + _k0 + scol,                \
                   (void*)(Bs + _b * 8192 + j * 4096 + wid * 512));           \
    }                                                                         \
  }

  // prologue: stage tiles 0,1; ensure tile 0 resident (tile 1 stays in flight)
  STAGE(0);
  STAGE(1);
  asm volatile("s_waitcnt vmcnt(6)" ::: "memory");
  __builtin_amdgcn_s_barrier();
  asm volatile("" ::: "memory");

  for (int t = 0; t < NT; ++t) {
    if (t + 2 < NT) STAGE(t + 2);

    const bf16_t* At  = As + (t % 3) * 16384;
    const bf16_t* Btl = Bs + (t % 3) * 8192;
    bf16x8 af[8][2], bfr[2][2];
#pragma unroll
    for (int m = 0; m < 8; ++m) {
      int row = wm * 128 + m * 16 + r15;
#pragma unroll
      for (int ks = 0; ks < 2; ++ks)
        af[m][ks] = *(const bf16x8*)&At[row * 64 + (((ks * 4 + g) ^ l7) * 8)];
    }
#pragma unroll
    for (int n = 0; n < 2; ++n) {
      int row = wn * 32 + n * 16 + r15;
#pragma unroll
      for (int ks = 0; ks < 2; ++ks)
        bfr[n][ks] = *(const bf16x8*)&Btl[row * 64 + (((ks * 4 + g) ^ l7) * 8)];
    }

    __builtin_amdgcn_s_setprio(1);
#pragma unroll
    for (int m = 0; m < 8; ++m)
#pragma unroll
      for (int n = 0; n < 2; ++n) {
        acc[m][n] = __builtin_amdgcn_mfma_f32_16x16x32_bf16(
            af[m][0], bfr[n][0], acc[m][n], 0, 0, 0);
        acc[m][n] = __builtin_amdgcn_mfma_f32_16x16x32_bf16(
            af[m][1], bfr[n][1], acc[m][n], 0, 0, 0);
      }
    __builtin_amdgcn_s_setprio(0);

    asm volatile("s_waitcnt vmcnt(6)" ::: "memory");
    __builtin_amdgcn_s_barrier();
    asm volatile("" ::: "memory");
  }
#undef STAGE

  // epilogue: bf16 store
#pragma unroll
  for (int m = 0; m < 8; ++m) {
#pragma unroll
    for (int n = 0; n < 2; ++n) {
      int col = bcol + wn * 32 + n * 16 + r15;
#pragma unroll
      for (int j = 0; j < 4; ++j) {
        int row = brow + wm * 128 + m * 16 + g * 4 + j;
        C[(size_t)row * N + col] = (bf16_t)acc[m][n][j];
      }
    }
  }
}

// ---------------------------------------------------------------------------
// BT GEMM (small): C[M,N] = A[M,K] * Bt[N,K]^T   (bf16 in, f32 accum)
// 128x128 tile, BK=64, 4 waves (2x2 of 64x64), mfma_f32_16x16x32_bf16
// EPI: 0 = store f32, 1 = softplus(x + bias[col]) f32, 2 = store bf16
// ---------------------------------------------------------------------------
template <int EPI>
__global__ __launch_bounds__(256)
void gemm_bt(const bf16_t* __restrict__ A, const bf16_t* __restrict__ Bt,
             void* __restrict__ C, const float* __restrict__ bias,
             int M, int N, int K) {
  __shared__ bf16_t Ash[128 * 64];
  __shared__ bf16_t Bsh[128 * 64];
  const int tid = threadIdx.x;
  const int wave = tid >> 6, lane = tid & 63;
  const int brow = blockIdx.y * 128, bcol = blockIdx.x * 128;
  const int wr = wave >> 1, wc = wave & 1;

  f32x4 acc[4][4] = {};

  const int seg_base = wave * 4;
  const int lrow = lane >> 3;          // 0..7 row within segment
  const int lcol = (lane & 7) * 8;     // bf16 col offset (8 bf16 = 16B)

  for (int k0 = 0; k0 < K; k0 += 64) {
#pragma unroll
    for (int c = 0; c < 4; ++c) {
      int seg = seg_base + c;
      int row = seg * 8 + lrow;
      const bf16_t* ga = A + (size_t)(brow + row) * K + k0 + lcol;
      load_lds_16B(ga, (void*)(Ash + seg * 512));
      const bf16_t* gb = Bt + (size_t)(bcol + row) * K + k0 + lcol;
      load_lds_16B(gb, (void*)(Bsh + seg * 512));
    }
    asm volatile("s_waitcnt vmcnt(0)");
    __syncthreads();

#pragma unroll
    for (int ks = 0; ks < 2; ++ks) {
      const int kk = ks * 32 + (lane >> 4) * 8;
      bf16x8 af[4], bfr[4];
#pragma unroll
      for (int t = 0; t < 4; ++t) {
        af[t]  = *(const bf16x8*)&Ash[(wr * 64 + t * 16 + (lane & 15)) * 64 + kk];
        bfr[t] = *(const bf16x8*)&Bsh[(wc * 64 + t * 16 + (lane & 15)) * 64 + kk];
      }
#pragma unroll
      for (int mt = 0; mt < 4; ++mt)
#pragma unroll
        for (int nt = 0; nt < 4; ++nt)
          acc[mt][nt] = __builtin_amdgcn_mfma_f32_16x16x32_bf16(
              af[mt], bfr[nt], acc[mt][nt], 0, 0, 0);
    }
    __syncthreads();
  }

#pragma unroll
  for (int mt = 0; mt < 4; ++mt) {
#pragma unroll
    for (int nt = 0; nt < 4; ++nt) {
      int col = bcol + wc * 64 + nt * 16 + (lane & 15);
#pragma unroll
      for (int j = 0; j < 4; ++j) {
        int row = brow + wr * 64 + mt * 16 + (lane >> 4) * 4 + j;
        float v = acc[mt][nt][j];
        size_t idx = (size_t)row * N + col;
        if (EPI == 0) {
          ((float*)C)[idx] = v;
        } else if (EPI == 1) {
          float x = v + bias[col];
          ((float*)C)[idx] = (x > 20.f) ? x : log1pf(__expf(x));
        } else {
          ((bf16_t*)C)[idx] = (bf16_t)v;
        }
      }
    }
  }
}

// ---------------------------------------------------------------------------
// depthwise causal conv(K=4) + bias + SiLU -> u (bf16); also gate = sigmoid
// proj layout: [BS, 4096]; u_pre = cols [0,2048), gate_pre = cols [2048,4096)
// ---------------------------------------------------------------------------
__global__ __launch_bounds__(256)
void conv_silu(const float* __restrict__ proj, const float* __restrict__ w_conv,
               const float* __restrict__ b_conv, bf16_t* __restrict__ u_bf,
               bf16_t* __restrict__ gate_bf) {
  int idx = blockIdx.x * 256 + threadIdx.x;     // over BATCH*SEQ*INNER
  int i = idx & (INNER - 1);
  int s = (idx >> 11) & (SEQ - 1);
  int b = idx >> 21;
  const float* up = proj + (size_t)b * SEQ * PROJ_N + i;  // column i, row stride PROJ_N
  float w0 = w_conv[i * 4 + 0], w1 = w_conv[i * 4 + 1];
  float w2 = w_conv[i * 4 + 2], w3 = w_conv[i * 4 + 3];
  float acc = b_conv[i];
  acc += up[(size_t)s * PROJ_N] * w3;
  if (s >= 1) acc += up[(size_t)(s - 1) * PROJ_N] * w2;
  if (s >= 2) acc += up[(size_t)(s - 2) * PROJ_N] * w1;
  if (s >= 3) acc += up[(size_t)(s - 3) * PROJ_N] * w0;
  float u = acc / (1.f + __expf(-acc));  // silu
  u_bf[idx] = (bf16_t)u;
  float gp = up[(size_t)s * PROJ_N + INNER];
  gate_bf[idx] = (bf16_t)(1.f / (1.f + __expf(-gp)));
}

// ---------------------------------------------------------------------------
// chunked selective scan, pass 1: per (b, i, chunk) lane over all 16 states:
//   E = chunk-local end state (zero init), P = prod of decays = exp(a*sum dt)
// ---------------------------------------------------------------------------
__global__ __launch_bounds__(256)
void scan_pass1(const float* __restrict__ delta, const bf16_t* __restrict__ u,
                const bf16_t* __restrict__ bmat, const float* __restrict__ a_log,
                float* __restrict__ P, float* __restrict__ E) {
  int t = blockIdx.x * 256 + threadIdx.x;    // B*NCHUNK*INNER lanes
  int i = t & (INNER - 1);
  int c = (t >> 11) & (NCHUNK - 1);
  int b = t >> 17;
  float an[STATE];
#pragma unroll
  for (int n = 0; n < STATE; ++n) an[n] = -__expf(a_log[i * STATE + n]);
  float st[STATE] = {};
  float dtsum = 0.f;
  size_t base_ch = (size_t)b * SEQ * INNER + i;
  size_t base_bc = (size_t)b * SEQ * BCN + (size_t)i * STATE;
  int s0 = c * CLEN;
  for (int s = s0; s < s0 + CLEN; ++s) {
    float dt = delta[base_ch + (size_t)s * INNER];
    float uv = (float)u[base_ch + (size_t)s * INNER];
    bf16x8 b0 = *(const bf16x8*)&bmat[base_bc + (size_t)s * BCN];
    bf16x8 b1 = *(const bf16x8*)&bmat[base_bc + (size_t)s * BCN + 8];
    float du = dt * uv;
    dtsum += dt;
#pragma unroll
    for (int n = 0; n < 8; ++n)
      st[n] = __expf(dt * an[n]) * st[n] + du * (float)b0[n];
#pragma unroll
    for (int n = 0; n < 8; ++n)
      st[8 + n] = __expf(dt * an[8 + n]) * st[8 + n] + du * (float)b1[n];
  }
  size_t pe = ((size_t)(b * NCHUNK + c) * INNER + i) * STATE;
#pragma unroll
  for (int q = 0; q < 4; ++q) {
    f32x4 vp = {__expf(dtsum * an[q * 4]), __expf(dtsum * an[q * 4 + 1]),
                __expf(dtsum * an[q * 4 + 2]), __expf(dtsum * an[q * 4 + 3])};
    *(f32x4*)&P[pe + q * 4] = vp;
    f32x4 ve = {st[q * 4], st[q * 4 + 1], st[q * 4 + 2], st[q * 4 + 3]};
    *(f32x4*)&E[pe + q * 4] = ve;
  }
}

// ---------------------------------------------------------------------------
// chunked scan, middle: sequential combine over chunks per (b,i,n).
// Overwrites E[c] with the TRUE initial state of chunk c.
// ---------------------------------------------------------------------------
__global__ __launch_bounds__(256)
void scan_mid(const float* __restrict__ P, float* __restrict__ E) {
  int g = blockIdx.x * 256 + threadIdx.x;    // B*INNER*STATE lanes
  int n = g & (STATE - 1);
  int i = (g >> 4) & (INNER - 1);
  int b = g >> 15;
  float H = 0.f;
  size_t stride = (size_t)INNER * STATE;
  size_t idx = (size_t)b * NCHUNK * stride + (size_t)i * STATE + n;
  for (int c = 0; c < NCHUNK; ++c) {
    float p = P[idx];
    float e = E[idx];
    E[idx] = H;
    H = p * H + e;
    idx += stride;
  }
}

// ---------------------------------------------------------------------------
// chunked scan, pass 2: re-run each chunk from its true initial state,
// emit y = (sum_n c_n * h_n + d*u) * gate  as bf16.
// ---------------------------------------------------------------------------
__global__ __launch_bounds__(256)
void scan_pass2(const float* __restrict__ delta, const bf16_t* __restrict__ u,
                const bf16_t* __restrict__ bmat, const bf16_t* __restrict__ cmat,
                const bf16_t* __restrict__ gate, const float* __restrict__ a_log,
                const float* __restrict__ dvec, const float* __restrict__ E,
                bf16_t* __restrict__ mixed) {
  int t = blockIdx.x * 256 + threadIdx.x;    // B*NCHUNK*INNER lanes
  int i = t & (INNER - 1);
  int c = (t >> 11) & (NCHUNK - 1);
  int b = t >> 17;
  float an[STATE];
#pragma unroll
  for (int n = 0; n < STATE; ++n) an[n] = -__expf(a_log[i * STATE + n]);
  float st[STATE];
  size_t pe = ((size_t)(b * NCHUNK + c) * INNER + i) * STATE;
#pragma unroll
  for (int q = 0; q < 4; ++q) {
    f32x4 v = *(const f32x4*)&E[pe + q * 4];
    st[q * 4] = v[0]; st[q * 4 + 1] = v[1]; st[q * 4 + 2] = v[2]; st[q * 4 + 3] = v[3];
  }
  float dd = dvec[i];
  size_t base_ch = (size_t)b * SEQ * INNER + i;
  size_t base_bc = (size_t)b * SEQ * BCN + (size_t)i * STATE;
  int s0 = c * CLEN;
  for (int s = s0; s < s0 + CLEN; ++s) {
    float dt = delta[base_ch + (size_t)s * INNER];
    float uv = (float)u[base_ch + (size_t)s * INNER];
    bf16x8 b0 = *(const bf16x8*)&bmat[base_bc + (size_t)s * BCN];
    bf16x8 b1 = *(const bf16x8*)&bmat[base_bc + (size_t)s * BCN + 8];
    bf16x8 c0 = *(const bf16x8*)&cmat[base_bc + (size_t)s * BCN];
    bf16x8 c1 = *(const bf16x8*)&cmat[base_bc + (size_t)s * BCN + 8];
    float du = dt * uv;
    float y = 0.f;
#pragma unroll
    for (int n = 0; n < 8; ++n) {
      st[n] = __expf(dt * an[n]) * st[n] + du * (float)b0[n];
      y += (float)c0[n] * st[n];
    }
#pragma unroll
    for (int n = 0; n < 8; ++n) {
      st[8 + n] = __expf(dt * an[8 + n]) * st[8 + n] + du * (float)b1[n];
      y += (float)c1[n] * st[8 + n];
    }
    float g = (float)gate[base_ch + (size_t)s * INNER];
    mixed[base_ch + (size_t)s * INNER] = (bf16_t)((y + dd * uv) * g);
  }
}

// ---------------------------------------------------------------------------
extern "C" void kernel_launch(void* const* d_in, const int* in_sizes, int n_in,
                              void* d_out, int out_size, void* d_ws, size_t ws_size,
                              hipStream_t stream) {
  const float* hidden = (const float*)d_in[0];
  const float* w_in   = (const float*)d_in[1];
  const float* w_conv = (const float*)d_in[2];
  const float* b_conv = (const float*)d_in[3];
  const float* w_dt   = (const float*)d_in[4];
  const float* b_dt   = (const float*)d_in[5];
  const float* w_b    = (const float*)d_in[6];
  const float* w_c    = (const float*)d_in[7];
  const float* w_out  = (const float*)d_in[8];
  const float* a_log  = (const float*)d_in[9];
  const float* dvec   = (const float*)d_in[10];
  float* out = (float*)d_out;

  char* ws = (char*)d_ws;
  bf16_t* hidden_bf = (bf16_t*)ws; ws += (size_t)BS * MODEL_DIM * 2;       // 4MB
  bf16_t* wsmall_bf = (bf16_t*)ws; ws += (size_t)PROJ_N * MODEL_DIM * 2;   // 8MB (w_in/w_dt/w_out share)
  float*  proj      = (float*)ws;  ws += (size_t)BS * PROJ_N * 4;          // 32MB
  bf16_t* u_bf      = (bf16_t*)ws; ws += (size_t)BS * INNER * 2;           // 8MB
  bf16_t* gate_bf   = (bf16_t*)ws; ws += (size_t)BS * INNER * 2;           // 8MB
  float*  delta     = (float*)ws;  ws += (size_t)BS * INNER * 4;           // 16MB
  bf16_t* wbig_bf   = (bf16_t*)ws; ws += (size_t)BCN * INNER * 2;          // 128MB (w_b/w_c share; P/E alias after)
  bf16_t* bmat      = (bf16_t*)ws; ws += (size_t)BS * BCN * 2;             // 128MB
  bf16_t* cmat      = (bf16_t*)ws; ws += (size_t)BS * BCN * 2;             // 128MB
  bf16_t* mixed     = (bf16_t*)ws; ws += (size_t)BS * INNER * 2;           // 8MB
  // P/E alias the (now unused) big-weight cast buffer during the scan
  float* Pbuf = (float*)wbig_bf;                                           // 16.8MB
  float* Ebuf = Pbuf + (size_t)BATCH * NCHUNK * INNER * STATE;             // 16.8MB

  // 1. cast hidden + w_in
  cast_f32_bf16<<<2048, 256, 0, stream>>>(hidden, hidden_bf, (long)BS * MODEL_DIM / 4);
  cast_f32_bf16<<<2048, 256, 0, stream>>>(w_in, wsmall_bf, (long)PROJ_N * MODEL_DIM / 4);
  // 2. proj = hidden @ w_in.T   [2048, 4096]
  gemm_bt<0><<<dim3(PROJ_N / 128, BS / 128), 256, 0, stream>>>(
      hidden_bf, wsmall_bf, proj, nullptr, BS, PROJ_N, MODEL_DIM);
  // 3. conv + silu -> u (bf16); gate = sigmoid (bf16)
  conv_silu<<<(BATCH * SEQ * INNER) / 256, 256, 0, stream>>>(proj, w_conv, b_conv, u_bf, gate_bf);
  // 4. delta = softplus(u @ w_dt.T + b_dt)   [2048, 2048] f32
  cast_f32_bf16<<<2048, 256, 0, stream>>>(w_dt, wsmall_bf, (long)INNER * INNER / 4);
  gemm_bt<1><<<dim3(INNER / 128, BS / 128), 256, 0, stream>>>(
      u_bf, wsmall_bf, delta, b_dt, BS, INNER, INNER);
  // 5. bmat = u @ w_b.T   [2048, 32768] bf16  (pipelined big kernel)
  cast_f32_bf16<<<2048, 256, 0, stream>>>(w_b, wbig_bf, (long)BCN * INNER / 4);
  gemm_big<<<2048, 512, 0, stream>>>(u_bf, wbig_bf, bmat, BCN, INNER);
  // 6. cmat = u @ w_c.T
  cast_f32_bf16<<<2048, 256, 0, stream>>>(w_c, wbig_bf, (long)BCN * INNER / 4);
  gemm_big<<<2048, 512, 0, stream>>>(u_bf, wbig_bf, cmat, BCN, INNER);
  // 7. chunked scan (P/E alias wbig_bf which is dead now)
  scan_pass1<<<(BATCH * NCHUNK * INNER) / 256, 256, 0, stream>>>(
      delta, u_bf, bmat, a_log, Pbuf, Ebuf);
  scan_mid<<<(BATCH * INNER * STATE) / 256, 256, 0, stream>>>(Pbuf, Ebuf);
  scan_pass2<<<(BATCH * NCHUNK * INNER) / 256, 256, 0, stream>>>(
      delta, u_bf, bmat, cmat, gate_bf, a_log, dvec, Ebuf, mixed);
  // 8. out = mixed @ w_out.T   [2048, 1024] f32
  cast_f32_bf16<<<2048, 256, 0, stream>>>(w_out, wsmall_bf, (long)MODEL_DIM * INNER / 4);
  gemm_bt<0><<<dim3(MODEL_DIM / 128, BS / 128), 256, 0, stream>>>(
      mixed, wsmall_bf, out, nullptr, BS, MODEL_DIM, INNER);
}

// Round 4
// 1111.405 us; speedup vs baseline: 1.2311x; 1.2311x over previous
//
#include <hip/hip_runtime.h>
#include <hip/hip_bf16.h>

typedef __bf16 bf16_t;
typedef __bf16 bf16x8 __attribute__((ext_vector_type(8)));
typedef float f32x4 __attribute__((ext_vector_type(4)));

#define MODEL_DIM 1024
#define INNER 2048
#define STATE 16
#define BATCH 2
#define SEQ 1024
#define BS (BATCH * SEQ)            // 2048 rows
#define PROJ_N (2 * INNER)          // 4096
#define BCN (INNER * STATE)         // 32768
#define NCHUNK 64
#define CLEN (SEQ / NCHUNK)         // 16

// ---------------------------------------------------------------------------
// async global->LDS, 16B per lane (wave-uniform LDS base, HW adds lane*16)
// ---------------------------------------------------------------------------
__device__ __forceinline__ void load_lds_16B(const void* g, void* l) {
  __builtin_amdgcn_global_load_lds(
      (const __attribute__((address_space(1))) unsigned int*)g,
      (__attribute__((address_space(3))) unsigned int*)l,
      16, 0, 0);
}

// ---------------------------------------------------------------------------
// f32 -> bf16 cast (vectorized, grid-stride). n must be divisible by 4.
// ---------------------------------------------------------------------------
__global__ void cast_f32_bf16(const float* __restrict__ in,
                              bf16_t* __restrict__ out, long n4) {
  long idx = (long)blockIdx.x * blockDim.x + threadIdx.x;
  long stride = (long)gridDim.x * blockDim.x;
  for (long i = idx; i < n4; i += stride) {
    float4 v = ((const float4*)in)[i];
    union { bf16_t b[4]; ushort4 u; } cv;
    cv.b[0] = (bf16_t)v.x; cv.b[1] = (bf16_t)v.y;
    cv.b[2] = (bf16_t)v.z; cv.b[3] = (bf16_t)v.w;
    ((ushort4*)out)[i] = cv.u;
  }
}

// ---------------------------------------------------------------------------
// BT GEMM: C[M,N] = A[M,K] * Bt[N,K]^T   (bf16 in, f32 accum)
// m97 structure: 128x128 tile, BK=64, 4 waves (2x2 of 64x64), vmcnt(0) drain.
// + T2 LDS XOR swizzle (16B slot ^= row&7, both sides: pre-swizzled global
//   source for global_load_lds, swizzled slot on ds_read)  [conflicts -> ~0]
// + T1 XCD-grouped 1-D grid (brow-fastest within each XCD for B-panel L2 reuse)
// EPI: 0 = store f32, 1 = softplus(x + bias[col]) f32, 2 = store bf16
// Grid: nbx*nby blocks, nbx % 8 == 0.
// ---------------------------------------------------------------------------
template <int EPI>
__global__ __launch_bounds__(256)
void gemm_bt(const bf16_t* __restrict__ A, const bf16_t* __restrict__ Bt,
             void* __restrict__ C, const float* __restrict__ bias,
             int nbx, int nby, int N, int K) {
  __shared__ bf16_t Ash[128 * 64];
  __shared__ bf16_t Bsh[128 * 64];
  const int tid = threadIdx.x;
  const int wave = tid >> 6, lane = tid & 63;

  // XCD-grouped mapping: xcd owns nbx/8 bcol-panels; brow iterates fastest
  const int bid = blockIdx.x;
  const int xcd = bid & 7, local = bid >> 3;
  const int bcol = (xcd * (nbx >> 3) + local / nby) * 128;
  const int brow = (local % nby) * 128;

  const int wr = wave >> 1, wc = wave & 1;

  f32x4 acc[4][4] = {};

  const int seg_base = wave * 4;
  const int lrow = lane >> 3;                        // 0..7 row within 8-row strip
  const int scol = ((lane & 7) ^ (lrow & 7)) * 8;    // pre-swizzled source col
  const int r15 = lane & 15, g = lane >> 4, l7 = lane & 7;

  for (int k0 = 0; k0 < K; k0 += 64) {
#pragma unroll
    for (int c = 0; c < 4; ++c) {
      int seg = seg_base + c;
      int row = seg * 8 + lrow;
      const bf16_t* ga = A + (size_t)(brow + row) * K + k0 + scol;
      load_lds_16B(ga, (void*)(Ash + seg * 512));
      const bf16_t* gb = Bt + (size_t)(bcol + row) * K + k0 + scol;
      load_lds_16B(gb, (void*)(Bsh + seg * 512));
    }
    asm volatile("s_waitcnt vmcnt(0)");
    __syncthreads();

#pragma unroll
    for (int ks = 0; ks < 2; ++ks) {
      bf16x8 af[4], bfr[4];
#pragma unroll
      for (int t = 0; t < 4; ++t) {
        int arow = wr * 64 + t * 16 + r15;
        int brw  = wc * 64 + t * 16 + r15;
        int slot = ((ks * 4 + g) ^ l7) * 8;          // swizzled 16B slot
        af[t]  = *(const bf16x8*)&Ash[arow * 64 + slot];
        bfr[t] = *(const bf16x8*)&Bsh[brw * 64 + slot];
      }
#pragma unroll
      for (int mt = 0; mt < 4; ++mt)
#pragma unroll
        for (int nt = 0; nt < 4; ++nt)
          acc[mt][nt] = __builtin_amdgcn_mfma_f32_16x16x32_bf16(
              af[mt], bfr[nt], acc[mt][nt], 0, 0, 0);
    }
    __syncthreads();
  }

#pragma unroll
  for (int mt = 0; mt < 4; ++mt) {
#pragma unroll
    for (int nt = 0; nt < 4; ++nt) {
      int col = bcol + wc * 64 + nt * 16 + r15;
#pragma unroll
      for (int j = 0; j < 4; ++j) {
        int row = brow + wr * 64 + mt * 16 + g * 4 + j;
        float v = acc[mt][nt][j];
        size_t idx = (size_t)row * N + col;
        if (EPI == 0) {
          ((float*)C)[idx] = v;
        } else if (EPI == 1) {
          float x = v + bias[col];
          ((float*)C)[idx] = (x > 20.f) ? x : log1pf(__expf(x));
        } else {
          ((bf16_t*)C)[idx] = (bf16_t)v;
        }
      }
    }
  }
}

// ---------------------------------------------------------------------------
// depthwise causal conv(K=4) + bias + SiLU -> u (bf16); also gate = sigmoid
// proj layout: [BS, 4096]; u_pre = cols [0,2048), gate_pre = cols [2048,4096)
// ---------------------------------------------------------------------------
__global__ __launch_bounds__(256)
void conv_silu(const float* __restrict__ proj, const float* __restrict__ w_conv,
               const float* __restrict__ b_conv, bf16_t* __restrict__ u_bf,
               bf16_t* __restrict__ gate_bf) {
  int idx = blockIdx.x * 256 + threadIdx.x;     // over BATCH*SEQ*INNER
  int i = idx & (INNER - 1);
  int s = (idx >> 11) & (SEQ - 1);
  int b = idx >> 21;
  const float* up = proj + (size_t)b * SEQ * PROJ_N + i;  // column i, row stride PROJ_N
  float w0 = w_conv[i * 4 + 0], w1 = w_conv[i * 4 + 1];
  float w2 = w_conv[i * 4 + 2], w3 = w_conv[i * 4 + 3];
  float acc = b_conv[i];
  acc += up[(size_t)s * PROJ_N] * w3;
  if (s >= 1) acc += up[(size_t)(s - 1) * PROJ_N] * w2;
  if (s >= 2) acc += up[(size_t)(s - 2) * PROJ_N] * w1;
  if (s >= 3) acc += up[(size_t)(s - 3) * PROJ_N] * w0;
  float u = acc / (1.f + __expf(-acc));  // silu
  u_bf[idx] = (bf16_t)u;
  float gp = up[(size_t)s * PROJ_N + INNER];
  gate_bf[idx] = (bf16_t)(1.f / (1.f + __expf(-gp)));
}

// ---------------------------------------------------------------------------
// chunked selective scan, pass 1: per (b, i, chunk) lane over all 16 states:
//   E = chunk-local end state (zero init), P = prod of decays = exp(a*sum dt)
// ---------------------------------------------------------------------------
__global__ __launch_bounds__(256)
void scan_pass1(const float* __restrict__ delta, const bf16_t* __restrict__ u,
                const bf16_t* __restrict__ bmat, const float* __restrict__ a_log,
                float* __restrict__ P, float* __restrict__ E) {
  int t = blockIdx.x * 256 + threadIdx.x;    // B*NCHUNK*INNER lanes
  int i = t & (INNER - 1);
  int c = (t >> 11) & (NCHUNK - 1);
  int b = t >> 17;
  float an[STATE];
#pragma unroll
  for (int n = 0; n < STATE; ++n) an[n] = -__expf(a_log[i * STATE + n]);
  float st[STATE] = {};
  float dtsum = 0.f;
  size_t base_ch = (size_t)b * SEQ * INNER + i;
  size_t base_bc = (size_t)b * SEQ * BCN + (size_t)i * STATE;
  int s0 = c * CLEN;
  for (int s = s0; s < s0 + CLEN; ++s) {
    float dt = delta[base_ch + (size_t)s * INNER];
    float uv = (float)u[base_ch + (size_t)s * INNER];
    bf16x8 b0 = *(const bf16x8*)&bmat[base_bc + (size_t)s * BCN];
    bf16x8 b1 = *(const bf16x8*)&bmat[base_bc + (size_t)s * BCN + 8];
    float du = dt * uv;
    dtsum += dt;
#pragma unroll
    for (int n = 0; n < 8; ++n)
      st[n] = __expf(dt * an[n]) * st[n] + du * (float)b0[n];
#pragma unroll
    for (int n = 0; n < 8; ++n)
      st[8 + n] = __expf(dt * an[8 + n]) * st[8 + n] + du * (float)b1[n];
  }
  size_t pe = ((size_t)(b * NCHUNK + c) * INNER + i) * STATE;
#pragma unroll
  for (int q = 0; q < 4; ++q) {
    f32x4 vp = {__expf(dtsum * an[q * 4]), __expf(dtsum * an[q * 4 + 1]),
                __expf(dtsum * an[q * 4 + 2]), __expf(dtsum * an[q * 4 + 3])};
    *(f32x4*)&P[pe + q * 4] = vp;
    f32x4 ve = {st[q * 4], st[q * 4 + 1], st[q * 4 + 2], st[q * 4 + 3]};
    *(f32x4*)&E[pe + q * 4] = ve;
  }
}

// ---------------------------------------------------------------------------
// chunked scan, middle: sequential combine over chunks per (b,i,n).
// Overwrites E[c] with the TRUE initial state of chunk c.
// ---------------------------------------------------------------------------
__global__ __launch_bounds__(256)
void scan_mid(const float* __restrict__ P, float* __restrict__ E) {
  int g = blockIdx.x * 256 + threadIdx.x;    // B*INNER*STATE lanes
  int n = g & (STATE - 1);
  int i = (g >> 4) & (INNER - 1);
  int b = g >> 15;
  float H = 0.f;
  size_t stride = (size_t)INNER * STATE;
  size_t idx = (size_t)b * NCHUNK * stride + (size_t)i * STATE + n;
  for (int c = 0; c < NCHUNK; ++c) {
    float p = P[idx];
    float e = E[idx];
    E[idx] = H;
    H = p * H + e;
    idx += stride;
  }
}

// ---------------------------------------------------------------------------
// chunked scan, pass 2: re-run each chunk from its true initial state,
// emit y = (sum_n c_n * h_n + d*u) * gate  as bf16.
// ---------------------------------------------------------------------------
__global__ __launch_bounds__(256)
void scan_pass2(const float* __restrict__ delta, const bf16_t* __restrict__ u,
                const bf16_t* __restrict__ bmat, const bf16_t* __restrict__ cmat,
                const bf16_t* __restrict__ gate, const float* __restrict__ a_log,
                const float* __restrict__ dvec, const float* __restrict__ E,
                bf16_t* __restrict__ mixed) {
  int t = blockIdx.x * 256 + threadIdx.x;    // B*NCHUNK*INNER lanes
  int i = t & (INNER - 1);
  int c = (t >> 11) & (NCHUNK - 1);
  int b = t >> 17;
  float an[STATE];
#pragma unroll
  for (int n = 0; n < STATE; ++n) an[n] = -__expf(a_log[i * STATE + n]);
  float st[STATE];
  size_t pe = ((size_t)(b * NCHUNK + c) * INNER + i) * STATE;
#pragma unroll
  for (int q = 0; q < 4; ++q) {
    f32x4 v = *(const f32x4*)&E[pe + q * 4];
    st[q * 4] = v[0]; st[q * 4 + 1] = v[1]; st[q * 4 + 2] = v[2]; st[q * 4 + 3] = v[3];
  }
  float dd = dvec[i];
  size_t base_ch = (size_t)b * SEQ * INNER + i;
  size_t base_bc = (size_t)b * SEQ * BCN + (size_t)i * STATE;
  int s0 = c * CLEN;
  for (int s = s0; s < s0 + CLEN; ++s) {
    float dt = delta[base_ch + (size_t)s * INNER];
    float uv = (float)u[base_ch + (size_t)s * INNER];
    bf16x8 b0 = *(const bf16x8*)&bmat[base_bc + (size_t)s * BCN];
    bf16x8 b1 = *(const bf16x8*)&bmat[base_bc + (size_t)s * BCN + 8];
    bf16x8 c0 = *(const bf16x8*)&cmat[base_bc + (size_t)s * BCN];
    bf16x8 c1 = *(const bf16x8*)&cmat[base_bc + (size_t)s * BCN + 8];
    float du = dt * uv;
    float y = 0.f;
#pragma unroll
    for (int n = 0; n < 8; ++n) {
      st[n] = __expf(dt * an[n]) * st[n] + du * (float)b0[n];
      y += (float)c0[n] * st[n];
    }
#pragma unroll
    for (int n = 0; n < 8; ++n) {
      st[8 + n] = __expf(dt * an[8 + n]) * st[8 + n] + du * (float)b1[n];
      y += (float)c1[n] * st[8 + n];
    }
    float g = (float)gate[base_ch + (size_t)s * INNER];
    mixed[base_ch + (size_t)s * INNER] = (bf16_t)((y + dd * uv) * g);
  }
}

// ---------------------------------------------------------------------------
extern "C" void kernel_launch(void* const* d_in, const int* in_sizes, int n_in,
                              void* d_out, int out_size, void* d_ws, size_t ws_size,
                              hipStream_t stream) {
  const float* hidden = (const float*)d_in[0];
  const float* w_in   = (const float*)d_in[1];
  const float* w_conv = (const float*)d_in[2];
  const float* b_conv = (const float*)d_in[3];
  const float* w_dt   = (const float*)d_in[4];
  const float* b_dt   = (const float*)d_in[5];
  const float* w_b    = (const float*)d_in[6];
  const float* w_c    = (const float*)d_in[7];
  const float* w_out  = (const float*)d_in[8];
  const float* a_log  = (const float*)d_in[9];
  const float* dvec   = (const float*)d_in[10];
  float* out = (float*)d_out;

  char* ws = (char*)d_ws;
  bf16_t* hidden_bf = (bf16_t*)ws; ws += (size_t)BS * MODEL_DIM * 2;       // 4MB
  bf16_t* wsmall_bf = (bf16_t*)ws; ws += (size_t)PROJ_N * MODEL_DIM * 2;   // 8MB (w_in/w_dt/w_out share)
  float*  proj      = (float*)ws;  ws += (size_t)BS * PROJ_N * 4;          // 32MB
  bf16_t* u_bf      = (bf16_t*)ws; ws += (size_t)BS * INNER * 2;           // 8MB
  bf16_t* gate_bf   = (bf16_t*)ws; ws += (size_t)BS * INNER * 2;           // 8MB
  float*  delta     = (float*)ws;  ws += (size_t)BS * INNER * 4;           // 16MB
  bf16_t* wbig_bf   = (bf16_t*)ws; ws += (size_t)BCN * INNER * 2;          // 128MB (w_b/w_c share; P/E alias after)
  bf16_t* bmat      = (bf16_t*)ws; ws += (size_t)BS * BCN * 2;             // 128MB
  bf16_t* cmat      = (bf16_t*)ws; ws += (size_t)BS * BCN * 2;             // 128MB
  bf16_t* mixed     = (bf16_t*)ws; ws += (size_t)BS * INNER * 2;           // 8MB
  // P/E alias the (now unused) big-weight cast buffer during the scan
  float* Pbuf = (float*)wbig_bf;                                           // 16.8MB
  float* Ebuf = Pbuf + (size_t)BATCH * NCHUNK * INNER * STATE;             // 16.8MB

  // 1. cast hidden + w_in
  cast_f32_bf16<<<2048, 256, 0, stream>>>(hidden, hidden_bf, (long)BS * MODEL_DIM / 4);
  cast_f32_bf16<<<2048, 256, 0, stream>>>(w_in, wsmall_bf, (long)PROJ_N * MODEL_DIM / 4);
  // 2. proj = hidden @ w_in.T   [2048, 4096]   nbx=32, nby=16
  gemm_bt<0><<<32 * 16, 256, 0, stream>>>(
      hidden_bf, wsmall_bf, proj, nullptr, 32, 16, PROJ_N, MODEL_DIM);
  // 3. conv + silu -> u (bf16); gate = sigmoid (bf16)
  conv_silu<<<(BATCH * SEQ * INNER) / 256, 256, 0, stream>>>(proj, w_conv, b_conv, u_bf, gate_bf);
  // 4. delta = softplus(u @ w_dt.T + b_dt)   [2048, 2048] f32   nbx=16, nby=16
  cast_f32_bf16<<<2048, 256, 0, stream>>>(w_dt, wsmall_bf, (long)INNER * INNER / 4);
  gemm_bt<1><<<16 * 16, 256, 0, stream>>>(
      u_bf, wsmall_bf, delta, b_dt, 16, 16, INNER, INNER);
  // 5. bmat = u @ w_b.T   [2048, 32768] bf16   nbx=256, nby=16
  cast_f32_bf16<<<2048, 256, 0, stream>>>(w_b, wbig_bf, (long)BCN * INNER / 4);
  gemm_bt<2><<<256 * 16, 256, 0, stream>>>(
      u_bf, wbig_bf, bmat, nullptr, 256, 16, BCN, INNER);
  // 6. cmat = u @ w_c.T
  cast_f32_bf16<<<2048, 256, 0, stream>>>(w_c, wbig_bf, (long)BCN * INNER / 4);
  gemm_bt<2><<<256 * 16, 256, 0, stream>>>(
      u_bf, wbig_bf, cmat, nullptr, 256, 16, BCN, INNER);
  // 7. chunked scan (P/E alias wbig_bf which is dead now)
  scan_pass1<<<(BATCH * NCHUNK * INNER) / 256, 256, 0, stream>>>(
      delta, u_bf, bmat, a_log, Pbuf, Ebuf);
  scan_mid<<<(BATCH * INNER * STATE) / 256, 256, 0, stream>>>(Pbuf, Ebuf);
  scan_pass2<<<(BATCH * NCHUNK * INNER) / 256, 256, 0, stream>>>(
      delta, u_bf, bmat, cmat, gate_bf, a_log, dvec, Ebuf, mixed);
  // 8. out = mixed @ w_out.T   [2048, 1024] f32   nbx=8, nby=16
  cast_f32_bf16<<<2048, 256, 0, stream>>>(w_out, wsmall_bf, (long)MODEL_DIM * INNER / 4);
  gemm_bt<0><<<8 * 16, 256, 0, stream>>>(
      mixed, wsmall_bf, out, nullptr, 8, 16, MODEL_DIM, INNER);
}

// Round 5
// 1091.927 us; speedup vs baseline: 1.2530x; 1.0178x over previous
//
#include <hip/hip_runtime.h>
#include <hip/hip_bf16.h>

typedef __bf16 bf16_t;
typedef __bf16 bf16x8 __attribute__((ext_vector_type(8)));
typedef float f32x4 __attribute__((ext_vector_type(4)));
typedef float f32x16 __attribute__((ext_vector_type(16)));

#define MODEL_DIM 1024
#define INNER 2048
#define STATE 16
#define BATCH 2
#define SEQ 1024
#define BS (BATCH * SEQ)            // 2048 rows
#define PROJ_N (2 * INNER)          // 4096
#define BCN (INNER * STATE)         // 32768
#define NCHUNK 64
#define CLEN (SEQ / NCHUNK)         // 16

// ---------------------------------------------------------------------------
// async global->LDS, 16B per lane (wave-uniform LDS base, HW adds lane*16)
// ---------------------------------------------------------------------------
__device__ __forceinline__ void load_lds_16B(const void* g, void* l) {
  __builtin_amdgcn_global_load_lds(
      (const __attribute__((address_space(1))) unsigned int*)g,
      (__attribute__((address_space(3))) unsigned int*)l,
      16, 0, 0);
}

// ---------------------------------------------------------------------------
// f32 -> bf16 cast (vectorized, grid-stride). n must be divisible by 4.
// ---------------------------------------------------------------------------
__global__ void cast_f32_bf16(const float* __restrict__ in,
                              bf16_t* __restrict__ out, long n4) {
  long idx = (long)blockIdx.x * blockDim.x + threadIdx.x;
  long stride = (long)gridDim.x * blockDim.x;
  for (long i = idx; i < n4; i += stride) {
    float4 v = ((const float4*)in)[i];
    union { bf16_t b[4]; ushort4 u; } cv;
    cv.b[0] = (bf16_t)v.x; cv.b[1] = (bf16_t)v.y;
    cv.b[2] = (bf16_t)v.z; cv.b[3] = (bf16_t)v.w;
    ((ushort4*)out)[i] = cv.u;
  }
}

// ---------------------------------------------------------------------------
// BT GEMM: C[M,N] = A[M,K] * Bt[N,K]^T   (bf16 in, f32 accum)
// 128x128 tile, BK=64, 4 waves (2x2 of 64x64), mfma_f32_32x32x16_bf16
// (2x2 frags of 32x32 per wave; fewer/denser MFMA than 16x16 variant).
// LDS XOR swizzle extended for 32-row fragment reads:
//   phys_slot = logical ^ (row&7) ^ (((row>>3)&3)<<1)   (both sides).
// XCD-grouped 1-D grid (brow fastest) for B-panel L2 reuse.
// EPI: 0 = store f32, 1 = softplus(x + bias[col]) f32, 2 = store bf16
// ---------------------------------------------------------------------------
template <int EPI>
__global__ __launch_bounds__(256)
void gemm_bt(const bf16_t* __restrict__ A, const bf16_t* __restrict__ Bt,
             void* __restrict__ C, const float* __restrict__ bias,
             int nbx, int nby, int N, int K) {
  __shared__ bf16_t Ash[128 * 64];
  __shared__ bf16_t Bsh[128 * 64];
  const int tid = threadIdx.x;
  const int wave = tid >> 6, lane = tid & 63;

  // XCD-grouped mapping: xcd owns nbx/8 bcol-panels; brow iterates fastest
  const int bid = blockIdx.x;
  const int xcd = bid & 7, local = bid >> 3;
  const int bcol = (xcd * (nbx >> 3) + local / nby) * 128;
  const int brow = (local % nby) * 128;

  const int wr = wave >> 1, wc = wave & 1;

  f32x16 acc[2][2] = {};

  const int lrow = lane >> 3;          // 0..7 row within 8-row strip
  const int l7 = lane & 7;
  const int r31 = lane & 31;
  const int h = lane >> 5;             // 0/1
  const int q = (lane >> 3) & 3;       // (row>>3)&3 contribution on read side

  for (int k0 = 0; k0 < K; k0 += 64) {
#pragma unroll
    for (int c = 0; c < 4; ++c) {
      int seg = wave * 4 + c;
      int row = seg * 8 + lrow;
      // pre-swizzled source slot: (l7 ^ lrow ^ ((seg&3)<<1)), seg&3 == c
      int scol = (l7 ^ lrow ^ (c << 1)) * 8;
      const bf16_t* ga = A + (size_t)(brow + row) * K + k0 + scol;
      load_lds_16B(ga, (void*)(Ash + seg * 512));
      const bf16_t* gb = Bt + (size_t)(bcol + row) * K + k0 + scol;
      load_lds_16B(gb, (void*)(Bsh + seg * 512));
    }
    asm volatile("s_waitcnt vmcnt(0)");
    __syncthreads();

    bf16x8 af[2][4], bfr[2][4];
#pragma unroll
    for (int m = 0; m < 2; ++m) {
      int row = wr * 64 + m * 32 + r31;
#pragma unroll
      for (int ks = 0; ks < 4; ++ks) {
        int phys = (ks * 2 + h) ^ l7 ^ (q << 1);
        af[m][ks] = *(const bf16x8*)&Ash[row * 64 + phys * 8];
      }
    }
#pragma unroll
    for (int n = 0; n < 2; ++n) {
      int row = wc * 64 + n * 32 + r31;
#pragma unroll
      for (int ks = 0; ks < 4; ++ks) {
        int phys = (ks * 2 + h) ^ l7 ^ (q << 1);
        bfr[n][ks] = *(const bf16x8*)&Bsh[row * 64 + phys * 8];
      }
    }

#pragma unroll
    for (int ks = 0; ks < 4; ++ks)
#pragma unroll
      for (int m = 0; m < 2; ++m)
#pragma unroll
        for (int n = 0; n < 2; ++n)
          acc[m][n] = __builtin_amdgcn_mfma_f32_32x32x16_bf16(
              af[m][ks], bfr[n][ks], acc[m][n], 0, 0, 0);
    __syncthreads();
  }

  // epilogue: C/D layout col = lane&31, row = (r&3) + 8*(r>>2) + 4*(lane>>5)
#pragma unroll
  for (int m = 0; m < 2; ++m) {
#pragma unroll
    for (int n = 0; n < 2; ++n) {
      int col = bcol + wc * 64 + n * 32 + r31;
#pragma unroll
      for (int r = 0; r < 16; ++r) {
        int row = brow + wr * 64 + m * 32 + (r & 3) + 8 * (r >> 2) + 4 * h;
        float v = acc[m][n][r];
        size_t idx = (size_t)row * N + col;
        if (EPI == 0) {
          ((float*)C)[idx] = v;
        } else if (EPI == 1) {
          float x = v + bias[col];
          ((float*)C)[idx] = (x > 20.f) ? x : log1pf(__expf(x));
        } else {
          ((bf16_t*)C)[idx] = (bf16_t)v;
        }
      }
    }
  }
}

// ---------------------------------------------------------------------------
// depthwise causal conv(K=4) + bias + SiLU -> u (bf16); also gate = sigmoid
// proj layout: [BS, 4096]; u_pre = cols [0,2048), gate_pre = cols [2048,4096)
// ---------------------------------------------------------------------------
__global__ __launch_bounds__(256)
void conv_silu(const float* __restrict__ proj, const float* __restrict__ w_conv,
               const float* __restrict__ b_conv, bf16_t* __restrict__ u_bf,
               bf16_t* __restrict__ gate_bf) {
  int idx = blockIdx.x * 256 + threadIdx.x;     // over BATCH*SEQ*INNER
  int i = idx & (INNER - 1);
  int s = (idx >> 11) & (SEQ - 1);
  int b = idx >> 21;
  const float* up = proj + (size_t)b * SEQ * PROJ_N + i;  // column i, row stride PROJ_N
  float w0 = w_conv[i * 4 + 0], w1 = w_conv[i * 4 + 1];
  float w2 = w_conv[i * 4 + 2], w3 = w_conv[i * 4 + 3];
  float acc = b_conv[i];
  acc += up[(size_t)s * PROJ_N] * w3;
  if (s >= 1) acc += up[(size_t)(s - 1) * PROJ_N] * w2;
  if (s >= 2) acc += up[(size_t)(s - 2) * PROJ_N] * w1;
  if (s >= 3) acc += up[(size_t)(s - 3) * PROJ_N] * w0;
  float u = acc / (1.f + __expf(-acc));  // silu
  u_bf[idx] = (bf16_t)u;
  float gp = up[(size_t)s * PROJ_N + INNER];
  gate_bf[idx] = (bf16_t)(1.f / (1.f + __expf(-gp)));
}

// ---------------------------------------------------------------------------
// chunked selective scan, pass 1: per (b, i, chunk) lane over all 16 states:
//   E = chunk-local end state (zero init), P = prod of decays = exp(a*sum dt)
// ---------------------------------------------------------------------------
__global__ __launch_bounds__(256)
void scan_pass1(const float* __restrict__ delta, const bf16_t* __restrict__ u,
                const bf16_t* __restrict__ bmat, const float* __restrict__ a_log,
                float* __restrict__ P, float* __restrict__ E) {
  int t = blockIdx.x * 256 + threadIdx.x;    // B*NCHUNK*INNER lanes
  int i = t & (INNER - 1);
  int c = (t >> 11) & (NCHUNK - 1);
  int b = t >> 17;
  float an[STATE];
#pragma unroll
  for (int n = 0; n < STATE; ++n) an[n] = -__expf(a_log[i * STATE + n]);
  float st[STATE] = {};
  float dtsum = 0.f;
  size_t base_ch = (size_t)b * SEQ * INNER + i;
  size_t base_bc = (size_t)b * SEQ * BCN + (size_t)i * STATE;
  int s0 = c * CLEN;
  for (int s = s0; s < s0 + CLEN; ++s) {
    float dt = delta[base_ch + (size_t)s * INNER];
    float uv = (float)u[base_ch + (size_t)s * INNER];
    bf16x8 b0 = *(const bf16x8*)&bmat[base_bc + (size_t)s * BCN];
    bf16x8 b1 = *(const bf16x8*)&bmat[base_bc + (size_t)s * BCN + 8];
    float du = dt * uv;
    dtsum += dt;
#pragma unroll
    for (int n = 0; n < 8; ++n)
      st[n] = __expf(dt * an[n]) * st[n] + du * (float)b0[n];
#pragma unroll
    for (int n = 0; n < 8; ++n)
      st[8 + n] = __expf(dt * an[8 + n]) * st[8 + n] + du * (float)b1[n];
  }
  size_t pe = ((size_t)(b * NCHUNK + c) * INNER + i) * STATE;
#pragma unroll
  for (int q = 0; q < 4; ++q) {
    f32x4 vp = {__expf(dtsum * an[q * 4]), __expf(dtsum * an[q * 4 + 1]),
                __expf(dtsum * an[q * 4 + 2]), __expf(dtsum * an[q * 4 + 3])};
    *(f32x4*)&P[pe + q * 4] = vp;
    f32x4 ve = {st[q * 4], st[q * 4 + 1], st[q * 4 + 2], st[q * 4 + 3]};
    *(f32x4*)&E[pe + q * 4] = ve;
  }
}

// ---------------------------------------------------------------------------
// chunked scan, middle: sequential combine over chunks per (b,i,n).
// Overwrites E[c] with the TRUE initial state of chunk c.
// ---------------------------------------------------------------------------
__global__ __launch_bounds__(256)
void scan_mid(const float* __restrict__ P, float* __restrict__ E) {
  int g = blockIdx.x * 256 + threadIdx.x;    // B*INNER*STATE lanes
  int n = g & (STATE - 1);
  int i = (g >> 4) & (INNER - 1);
  int b = g >> 15;
  float H = 0.f;
  size_t stride = (size_t)INNER * STATE;
  size_t idx = (size_t)b * NCHUNK * stride + (size_t)i * STATE + n;
  for (int c = 0; c < NCHUNK; ++c) {
    float p = P[idx];
    float e = E[idx];
    E[idx] = H;
    H = p * H + e;
    idx += stride;
  }
}

// ---------------------------------------------------------------------------
// chunked scan, pass 2: re-run each chunk from its true initial state,
// emit y = (sum_n c_n * h_n + d*u) * gate  as bf16.
// ---------------------------------------------------------------------------
__global__ __launch_bounds__(256)
void scan_pass2(const float* __restrict__ delta, const bf16_t* __restrict__ u,
                const bf16_t* __restrict__ bmat, const bf16_t* __restrict__ cmat,
                const bf16_t* __restrict__ gate, const float* __restrict__ a_log,
                const float* __restrict__ dvec, const float* __restrict__ E,
                bf16_t* __restrict__ mixed) {
  int t = blockIdx.x * 256 + threadIdx.x;    // B*NCHUNK*INNER lanes
  int i = t & (INNER - 1);
  int c = (t >> 11) & (NCHUNK - 1);
  int b = t >> 17;
  float an[STATE];
#pragma unroll
  for (int n = 0; n < STATE; ++n) an[n] = -__expf(a_log[i * STATE + n]);
  float st[STATE];
  size_t pe = ((size_t)(b * NCHUNK + c) * INNER + i) * STATE;
#pragma unroll
  for (int q = 0; q < 4; ++q) {
    f32x4 v = *(const f32x4*)&E[pe + q * 4];
    st[q * 4] = v[0]; st[q * 4 + 1] = v[1]; st[q * 4 + 2] = v[2]; st[q * 4 + 3] = v[3];
  }
  float dd = dvec[i];
  size_t base_ch = (size_t)b * SEQ * INNER + i;
  size_t base_bc = (size_t)b * SEQ * BCN + (size_t)i * STATE;
  int s0 = c * CLEN;
  for (int s = s0; s < s0 + CLEN; ++s) {
    float dt = delta[base_ch + (size_t)s * INNER];
    float uv = (float)u[base_ch + (size_t)s * INNER];
    bf16x8 b0 = *(const bf16x8*)&bmat[base_bc + (size_t)s * BCN];
    bf16x8 b1 = *(const bf16x8*)&bmat[base_bc + (size_t)s * BCN + 8];
    bf16x8 c0 = *(const bf16x8*)&cmat[base_bc + (size_t)s * BCN];
    bf16x8 c1 = *(const bf16x8*)&cmat[base_bc + (size_t)s * BCN + 8];
    float du = dt * uv;
    float y = 0.f;
#pragma unroll
    for (int n = 0; n < 8; ++n) {
      st[n] = __expf(dt * an[n]) * st[n] + du * (float)b0[n];
      y += (float)c0[n] * st[n];
    }
#pragma unroll
    for (int n = 0; n < 8; ++n) {
      st[8 + n] = __expf(dt * an[8 + n]) * st[8 + n] + du * (float)b1[n];
      y += (float)c1[n] * st[8 + n];
    }
    float g = (float)gate[base_ch + (size_t)s * INNER];
    mixed[base_ch + (size_t)s * INNER] = (bf16_t)((y + dd * uv) * g);
  }
}

// ---------------------------------------------------------------------------
extern "C" void kernel_launch(void* const* d_in, const int* in_sizes, int n_in,
                              void* d_out, int out_size, void* d_ws, size_t ws_size,
                              hipStream_t stream) {
  const float* hidden = (const float*)d_in[0];
  const float* w_in   = (const float*)d_in[1];
  const float* w_conv = (const float*)d_in[2];
  const float* b_conv = (const float*)d_in[3];
  const float* w_dt   = (const float*)d_in[4];
  const float* b_dt   = (const float*)d_in[5];
  const float* w_b    = (const float*)d_in[6];
  const float* w_c    = (const float*)d_in[7];
  const float* w_out  = (const float*)d_in[8];
  const float* a_log  = (const float*)d_in[9];
  const float* dvec   = (const float*)d_in[10];
  float* out = (float*)d_out;

  char* ws = (char*)d_ws;
  bf16_t* hidden_bf = (bf16_t*)ws; ws += (size_t)BS * MODEL_DIM * 2;       // 4MB
  bf16_t* wsmall_bf = (bf16_t*)ws; ws += (size_t)PROJ_N * MODEL_DIM * 2;   // 8MB (w_in/w_dt/w_out share)
  float*  proj      = (float*)ws;  ws += (size_t)BS * PROJ_N * 4;          // 32MB
  bf16_t* u_bf      = (bf16_t*)ws; ws += (size_t)BS * INNER * 2;           // 8MB
  bf16_t* gate_bf   = (bf16_t*)ws; ws += (size_t)BS * INNER * 2;           // 8MB
  float*  delta     = (float*)ws;  ws += (size_t)BS * INNER * 4;           // 16MB
  bf16_t* wbig_bf   = (bf16_t*)ws; ws += (size_t)BCN * INNER * 2;          // 128MB (w_b/w_c share; P/E alias after)
  bf16_t* bmat      = (bf16_t*)ws; ws += (size_t)BS * BCN * 2;             // 128MB
  bf16_t* cmat      = (bf16_t*)ws; ws += (size_t)BS * BCN * 2;             // 128MB
  bf16_t* mixed     = (bf16_t*)ws; ws += (size_t)BS * INNER * 2;           // 8MB
  // P/E alias the (now unused) big-weight cast buffer during the scan
  float* Pbuf = (float*)wbig_bf;                                           // 16.8MB
  float* Ebuf = Pbuf + (size_t)BATCH * NCHUNK * INNER * STATE;             // 16.8MB

  // 1. cast hidden + w_in
  cast_f32_bf16<<<2048, 256, 0, stream>>>(hidden, hidden_bf, (long)BS * MODEL_DIM / 4);
  cast_f32_bf16<<<2048, 256, 0, stream>>>(w_in, wsmall_bf, (long)PROJ_N * MODEL_DIM / 4);
  // 2. proj = hidden @ w_in.T   [2048, 4096]   nbx=32, nby=16
  gemm_bt<0><<<32 * 16, 256, 0, stream>>>(
      hidden_bf, wsmall_bf, proj, nullptr, 32, 16, PROJ_N, MODEL_DIM);
  // 3. conv + silu -> u (bf16); gate = sigmoid (bf16)
  conv_silu<<<(BATCH * SEQ * INNER) / 256, 256, 0, stream>>>(proj, w_conv, b_conv, u_bf, gate_bf);
  // 4. delta = softplus(u @ w_dt.T + b_dt)   [2048, 2048] f32   nbx=16, nby=16
  cast_f32_bf16<<<2048, 256, 0, stream>>>(w_dt, wsmall_bf, (long)INNER * INNER / 4);
  gemm_bt<1><<<16 * 16, 256, 0, stream>>>(
      u_bf, wsmall_bf, delta, b_dt, 16, 16, INNER, INNER);
  // 5. bmat = u @ w_b.T   [2048, 32768] bf16   nbx=256, nby=16
  cast_f32_bf16<<<2048, 256, 0, stream>>>(w_b, wbig_bf, (long)BCN * INNER / 4);
  gemm_bt<2><<<256 * 16, 256, 0, stream>>>(
      u_bf, wbig_bf, bmat, nullptr, 256, 16, BCN, INNER);
  // 6. cmat = u @ w_c.T
  cast_f32_bf16<<<2048, 256, 0, stream>>>(w_c, wbig_bf, (long)BCN * INNER / 4);
  gemm_bt<2><<<256 * 16, 256, 0, stream>>>(
      u_bf, wbig_bf, cmat, nullptr, 256, 16, BCN, INNER);
  // 7. chunked scan (P/E alias wbig_bf which is dead now)
  scan_pass1<<<(BATCH * NCHUNK * INNER) / 256, 256, 0, stream>>>(
      delta, u_bf, bmat, a_log, Pbuf, Ebuf);
  scan_mid<<<(BATCH * INNER * STATE) / 256, 256, 0, stream>>>(Pbuf, Ebuf);
  scan_pass2<<<(BATCH * NCHUNK * INNER) / 256, 256, 0, stream>>>(
      delta, u_bf, bmat, cmat, gate_bf, a_log, dvec, Ebuf, mixed);
  // 8. out = mixed @ w_out.T   [2048, 1024] f32   nbx=8, nby=16
  cast_f32_bf16<<<2048, 256, 0, stream>>>(w_out, wsmall_bf, (long)MODEL_DIM * INNER / 4);
  gemm_bt<0><<<8 * 16, 256, 0, stream>>>(
      mixed, wsmall_bf, out, nullptr, 8, 16, MODEL_DIM, INNER);
}